// Round 3
// baseline (379.728 us; speedup 1.0000x reference)
//
#include <hip/hip_runtime.h>

#define NN 100000
#define NE 1600000
#define D 128
#define RT 64
#define NB 196      // dst buckets of 512 nodes: ceil(100000/512)
#define CAP 9216    // per-bucket edge cap: mean 8192, sd ~90 -> +11 sigma
#define PADB 136    // bf16 elems per LDS row: b128 frag reads 2-way (free)
#define PB 12503    // blocks 0..PB-1: x convert + W transpose; then bucket blocks
#define BUCKB 391   // bucket blocks x 4096 edges = 1601536 >= NE

typedef unsigned short u16;
typedef __attribute__((ext_vector_type(8))) short bf16x8;
typedef __attribute__((ext_vector_type(4))) float f32x4;

__device__ __forceinline__ u16 f2bf(float f) {          // RNE fp32->bf16
  unsigned int u = __float_as_uint(f);
  u += 0x7fffu + ((u >> 16) & 1u);
  return (u16)(u >> 16);
}

// ---- prep + bucket fused: bucket's atomic latency hides under prep streaming
__global__ __launch_bounds__(256) void prep_bucket_kernel(
    const float* __restrict__ x, const int* __restrict__ ei,
    const float* __restrict__ W1, const float* __restrict__ W2,
    const float* __restrict__ Wres,
    u16* __restrict__ xh, u16* __restrict__ wt,
    int* __restrict__ tail, unsigned* __restrict__ buf) {
  __shared__ int lhist[NB], lbase[NB];
  int b = blockIdx.x;
  int t = threadIdx.x;
  if (b < 12500) {                     // x convert: 3.2M float4s
    int q = b * 256 + t;
    float4 v = ((const float4*)x)[q];
    uint2 pk;
    pk.x = (unsigned)f2bf(v.x) | ((unsigned)f2bf(v.y) << 16);
    pk.y = (unsigned)f2bf(v.z) | ((unsigned)f2bf(v.w) << 16);
    ((uint2*)xh)[q] = pk;
  } else if (b < PB) {                 // W transpose: order [Wres, W1, W2]
    const float* W = (b == 12500) ? Wres : (b == 12501) ? W1 : W2;
    u16* dst = wt + (size_t)(b - 12500) * 16384;
    for (int i = t; i < 16384; i += 256) {
      int n = i >> 7, k = i & 127;
      dst[i] = f2bf(W[k * 128 + n]);   // dst[n*128+k]
    }
  } else {                             // bucket edges by dst>>9 (tail pre-zeroed)
    size_t e0 = (size_t)(b - PB) * 4096;
    int s[16], d[16];
    for (int j = t; j < NB; j += 256) lhist[j] = 0;
    __syncthreads();
#pragma unroll
    for (int k = 0; k < 16; ++k) {
      size_t e = e0 + t + (size_t)k * 256;
      if (e < NE) {
        d[k] = ei[NE + e];             // dst
        s[k] = ei[e];                  // src
        atomicAdd(&lhist[d[k] >> 9], 1);  // LDS, no-return -> ds_add
      } else {
        d[k] = -1;
      }
    }
    __syncthreads();
    for (int j = t; j < NB; j += 256) {  // reserve contiguous run per bucket
      int c = lhist[j];
      lbase[j] = c ? atomicAdd(&tail[j], c) : 0;
      lhist[j] = 0;
    }
    __syncthreads();
#pragma unroll
    for (int k = 0; k < 16; ++k) {
      if (d[k] >= 0) {
        int bk = d[k] >> 9;
        int r = lbase[bk] + atomicAdd(&lhist[bk], 1);
        if (r < CAP)
          buf[(size_t)bk * CAP + r] = (unsigned)s[k] | ((unsigned)(d[k] & 511) << 17);
      }
    }
  }
}

// ---------------- per-bucket CSR build, all atomics in LDS ----------------
__global__ __launch_bounds__(512) void build_csr(const unsigned* __restrict__ buf,
                                                 const int* __restrict__ tail,
                                                 int* __restrict__ cnt,
                                                 int* __restrict__ start,
                                                 int* __restrict__ csr) {
  __shared__ int lhist[512], lpre[512], lsum[64];
  int b = blockIdx.x, t = threadIdx.x;
  int nE = tail[b];
  if (nE > CAP) nE = CAP;
  size_t bBase = (size_t)b * CAP;
  lhist[t] = 0;
  __syncthreads();
  for (int i = t; i < nE; i += 512)
    atomicAdd(&lhist[buf[bBase + i] >> 17], 1);
  __syncthreads();
  if (t < 64) {
    int s = 0;
#pragma unroll
    for (int k = 0; k < 8; ++k) { int v = lhist[t * 8 + k]; lpre[t * 8 + k] = s; s += v; }
    lsum[t] = s;
  }
  __syncthreads();
  if (t == 0) {
    int s = 0;
    for (int k = 0; k < 64; ++k) { int v = lsum[k]; lsum[k] = s; s += v; }
  }
  __syncthreads();
  if (t < 64) {
    int o = lsum[t];
#pragma unroll
    for (int k = 0; k < 8; ++k) lpre[t * 8 + k] += o;
  }
  __syncthreads();
  int node = (b << 9) + t;
  if (node < NN) {
    cnt[node] = lhist[t];
    start[node] = (int)bBase + lpre[t];
  }
  lhist[t] = 0;
  __syncthreads();
  for (int i = t; i < nE; i += 512) {
    unsigned e = buf[bBase + i];
    int dl = e >> 17;
    int r = atomicAdd(&lhist[dl], 1);                 // LDS rank
    csr[bBase + lpre[dl] + r] = (int)(e & 0x1FFFFu);  // L2-resident 36KB window
  }
}

// ---- gather: h0h[n] = bf16(x[n] + sum xh[csr[...]]) -> first 256B of out row
// 16 lanes x uint4(16B) per row: half the loads, 2x outstanding bytes vs 32x8B.
#define BFACC8(aL, aH, v)                                  \
  { aL.x += __uint_as_float((v).x << 16);                  \
    aL.y += __uint_as_float((v).x & 0xffff0000u);          \
    aL.z += __uint_as_float((v).y << 16);                  \
    aL.w += __uint_as_float((v).y & 0xffff0000u);          \
    aH.x += __uint_as_float((v).z << 16);                  \
    aH.y += __uint_as_float((v).z & 0xffff0000u);          \
    aH.z += __uint_as_float((v).w << 16);                  \
    aH.w += __uint_as_float((v).w & 0xffff0000u); }

__global__ __launch_bounds__(256, 6) void gather_kernel(const float* __restrict__ x,
                                                        const u16* __restrict__ xh,
                                                        const int* __restrict__ cnt,
                                                        const int* __restrict__ start,
                                                        const int* __restrict__ csr,
                                                        u16* __restrict__ h0h) {
  int g = blockIdx.x * 16 + (threadIdx.x >> 4);
  if (g >= NN) return;
  int lane = threadIdx.x & 15;
  int fo = lane * 8;                   // u16 units: 16 B per lane
  int n = cnt[g];
  const int* sp = csr + start[g];

  float4 aL0 = make_float4(0.f, 0.f, 0.f, 0.f);
  float4 aH0 = aL0, aL1 = aL0, aH1 = aL0;

  int nfull = n & ~3;
  if (nfull > 0) {
    int s0 = sp[0], s1 = sp[1], s2 = sp[2], s3 = sp[3];
    uint4 v0 = *(const uint4*)&xh[(size_t)s0 * D + fo];
    uint4 v1 = *(const uint4*)&xh[(size_t)s1 * D + fo];
    uint4 v2 = *(const uint4*)&xh[(size_t)s2 * D + fo];
    uint4 v3 = *(const uint4*)&xh[(size_t)s3 * D + fo];
#pragma unroll 2
    for (int j = 4; j < nfull; j += 4) {
      int t0 = sp[j], t1 = sp[j + 1], t2 = sp[j + 2], t3 = sp[j + 3];
      uint4 w0 = *(const uint4*)&xh[(size_t)t0 * D + fo];
      uint4 w1 = *(const uint4*)&xh[(size_t)t1 * D + fo];
      uint4 w2 = *(const uint4*)&xh[(size_t)t2 * D + fo];
      uint4 w3 = *(const uint4*)&xh[(size_t)t3 * D + fo];
      BFACC8(aL0, aH0, v0); BFACC8(aL1, aH1, v1);
      BFACC8(aL0, aH0, v2); BFACC8(aL1, aH1, v3);
      v0 = w0; v1 = w1; v2 = w2; v3 = w3;
    }
    BFACC8(aL0, aH0, v0); BFACC8(aL1, aH1, v1);
    BFACC8(aL0, aH0, v2); BFACC8(aL1, aH1, v3);
  }
  for (int j = nfull; j < n; ++j) {
    uint4 v0 = *(const uint4*)&xh[(size_t)sp[j] * D + fo];
    BFACC8(aL0, aH0, v0);
  }

  const float* xp = &x[(size_t)g * D + fo];   // self term exact
  float4 x0 = *(const float4*)xp;
  float4 x1 = *(const float4*)(xp + 4);
  float h0 = x0.x + aL0.x + aL1.x;
  float h1 = x0.y + aL0.y + aL1.y;
  float h2 = x0.z + aL0.z + aL1.z;
  float h3 = x0.w + aL0.w + aL1.w;
  float h4 = x1.x + aH0.x + aH1.x;
  float h5 = x1.y + aH0.y + aH1.y;
  float h6 = x1.z + aH0.z + aH1.z;
  float h7 = x1.w + aH0.w + aH1.w;
  uint4 pk;
  pk.x = (unsigned)f2bf(h0) | ((unsigned)f2bf(h1) << 16);
  pk.y = (unsigned)f2bf(h2) | ((unsigned)f2bf(h3) << 16);
  pk.z = (unsigned)f2bf(h4) | ((unsigned)f2bf(h5) << 16);
  pk.w = (unsigned)f2bf(h6) | ((unsigned)f2bf(h7) << 16);
  *(uint4*)&h0h[(size_t)g * 256 + fo] = pk;   // row stride 256 u16 = 512 B
}

// ---------------- fused MFMA: 3 GEMMs + ReLU + LN + residual ----------------
// Hs staged from bf16 h0h; Wres GEMM A-frags straight from global xh (L3-hot).
// 3 barriers. C/D layout (verified): col=lane&15, row=(lane>>4)*4+reg.
__global__ __launch_bounds__(256, 6) void fused_kernel(
    const u16* __restrict__ xh, const u16* __restrict__ h0h,
    const u16* __restrict__ wt,
    const float* __restrict__ b1, const float* __restrict__ b2,
    const float* __restrict__ gamma, const float* __restrict__ beta,
    const float* __restrict__ bres, float* __restrict__ out) {
  __shared__ u16 Hs[RT * PADB];   // 17408 B

  const int t = threadIdx.x;
  const int w = t >> 6;
  const int lane = t & 63;
  const int quad = lane >> 4;
  const int l16 = lane & 15;
  const int row0 = blockIdx.x * RT;

  // stage Hs <- h0h (bf16 rows, stride 256 u16)
#pragma unroll
  for (int i = 0; i < 8; ++i) {
    int v = t + i * 256;
    int r = v >> 5;
    int c4 = (v & 31) << 2;
    int row = row0 + r;
    uint2 val = make_uint2(0u, 0u);
    if (row < NN) val = *(const uint2*)&h0h[(size_t)row * 256 + c4];
    *(uint2*)&Hs[r * PADB + c4] = val;
  }

  f32x4 acc[8], accR[8];
  f32x4 zz = {0.f, 0.f, 0.f, 0.f};
#pragma unroll
  for (int i = 0; i < 8; ++i) { acc[i] = zz; accR[i] = zz; }

  auto gemmL = [&](const u16* __restrict__ W, f32x4 (&dd)[8]) {   // A from LDS
    bf16x8 af[4];
#pragma unroll
    for (int s = 0; s < 4; ++s)
      af[s] = *(const bf16x8*)&Hs[(w * 16 + l16) * PADB + s * 32 + quad * 8];
#pragma unroll
    for (int nt = 0; nt < 8; ++nt) {
      const u16* wp = W + (size_t)(nt * 16 + l16) * D + quad * 8;
#pragma unroll
      for (int s = 0; s < 4; ++s) {
        bf16x8 bf = *(const bf16x8*)&wp[s * 32];
        dd[nt] = __builtin_amdgcn_mfma_f32_16x16x32_bf16(af[s], bf, dd[nt], 0, 0, 0);
      }
    }
  };

  {  // Wres GEMM: A straight from global xh (overlaps the stage, pre-barrier)
    bf16x8 af[4];
#pragma unroll
    for (int s = 0; s < 4; ++s)
      af[s] = *(const bf16x8*)&xh[(size_t)(row0 + w * 16 + l16) * D + s * 32 + quad * 8];
#pragma unroll
    for (int nt = 0; nt < 8; ++nt) {
      const u16* wp = wt + (size_t)(nt * 16 + l16) * D + quad * 8;
#pragma unroll
      for (int s = 0; s < 4; ++s) {
        bf16x8 bf = *(const bf16x8*)&wp[s * 32];
        accR[nt] = __builtin_amdgcn_mfma_f32_16x16x32_bf16(af[s], bf, accR[nt], 0, 0, 0);
      }
    }
  }

  __syncthreads();                // Hs ready
  gemmL(wt + 16384, acc);         // W1 on Hs
  __syncthreads();                // af loads done before Hs overwrite

  // ---- h1 = relu(acc + b1) -> Hs (C-layout scatter, bf16) ----
#pragma unroll
  for (int nt = 0; nt < 8; ++nt) {
    int col = nt * 16 + l16;
    float bb = b1[col];
#pragma unroll
    for (int r = 0; r < 4; ++r) {
      float hv = acc[nt][r] + bb;
      hv = hv > 0.f ? hv : 0.f;
      Hs[(w * 16 + quad * 4 + r) * PADB + col] = f2bf(hv);
      acc[nt][r] = 0.f;
    }
  }
  __syncthreads();
  gemmL(wt + 32768, acc);         // W2

  // ---- epilogue: +b2, LayerNorm (shuffle over 16-lane quad), + residual ----
  float b2v[8], gv[8], bev[8], brv[8];
#pragma unroll
  for (int nt = 0; nt < 8; ++nt) {
    int col = nt * 16 + l16;
    b2v[nt] = b2[col];
    gv[nt] = gamma[col];
    bev[nt] = beta[col];
    brv[nt] = bres[col];
  }
#pragma unroll
  for (int r = 0; r < 4; ++r) {
    float s = 0.f, s2 = 0.f;
#pragma unroll
    for (int nt = 0; nt < 8; ++nt) {
      float h = acc[nt][r] + b2v[nt];
      s += h;
      s2 += h * h;
    }
    for (int m = 1; m <= 8; m <<= 1) {   // reduce across the quad's 16 lanes
      s += __shfl_xor(s, m);
      s2 += __shfl_xor(s2, m);
    }
    float mu = s * 0.0078125f;
    float var = s2 * 0.0078125f - mu * mu;
    float rs = rsqrtf(var + 1e-5f);
    int row = row0 + w * 16 + quad * 4 + r;
    if (row < NN) {
#pragma unroll
      for (int nt = 0; nt < 8; ++nt) {
        float h = acc[nt][r] + b2v[nt];
        out[(size_t)row * D + nt * 16 + l16] =
            (h - mu) * rs * gv[nt] + bev[nt] + accR[nt][r] + brv[nt];
      }
    }
  }
}

extern "C" void kernel_launch(void* const* d_in, const int* in_sizes, int n_in,
                              void* d_out, int out_size, void* d_ws, size_t ws_size,
                              hipStream_t stream) {
  const float* x     = (const float*)d_in[0];
  const int*   ei    = (const int*)d_in[1];
  const float* W1    = (const float*)d_in[2];
  const float* b1    = (const float*)d_in[3];
  const float* W2    = (const float*)d_in[4];
  const float* b2    = (const float*)d_in[5];
  const float* gamma = (const float*)d_in[6];
  const float* beta  = (const float*)d_in[7];
  const float* Wres  = (const float*)d_in[8];
  const float* bres  = (const float*)d_in[9];
  float* out = (float*)d_out;

  // ws: tail 1KB | buf 7.2MB | cnt 0.4 | start 0.4 | csr 7.2 | xh 25.6 | wt 96KB
  int*      tail  = (int*)d_ws;                              // 256 (NB=196 used)
  unsigned* buf   = (unsigned*)(tail + 256);                 // NB*CAP
  int*      cnt   = (int*)(buf + (size_t)NB * CAP);          // NN
  int*      start = cnt + NN;                                // NN
  int*      csr   = start + NN;                              // NB*CAP
  u16*      xh    = (u16*)(csr + (size_t)NB * CAP);          // NN*D bf16
  u16*      wt    = xh + (size_t)NN * D;                     // 3*128*128 bf16

  // h0 (bf16) lives in the first 256 B of each 512 B out-row slot: block i of
  // fused reads exactly the rows it later overwrites -> race-free.
  u16* h0h = (u16*)out;

  hipMemsetAsync(tail, 0, 256 * sizeof(int), stream);
  prep_bucket_kernel<<<PB + BUCKB, 256, 0, stream>>>(x, ei, W1, W2, Wres,
                                                     xh, wt, tail, buf);
  build_csr<<<NB, 512, 0, stream>>>(buf, tail, cnt, start, csr);
  gather_kernel<<<(NN + 15) / 16, 256, 0, stream>>>(x, xh, cnt, start, csr, h0h);
  fused_kernel<<<(NN + RT - 1) / RT, 256, 0, stream>>>(
      xh, h0h, wt, b1, b2, gamma, beta, bres, out);
}

// Round 4
// 317.715 us; speedup vs baseline: 1.1952x; 1.1952x over previous
//
#include <hip/hip_runtime.h>

#define NN 100000
#define NE 1600000
#define D 128
#define RT 64
#define NB 196      // dst buckets of 512 nodes: ceil(100000/512)
#define CAP 9216    // per-bucket edge cap: mean 8192, sd ~90 -> +11 sigma
#define PADB 136    // bf16 elems per LDS row: b128 frag reads 2-way (free)
#define PB 12503    // blocks 0..PB-1: x convert + W transpose; then bucket blocks
#define BUCKB 391   // bucket blocks x 4096 edges = 1601536 >= NE

typedef unsigned short u16;
typedef __attribute__((ext_vector_type(8))) short bf16x8;
typedef __attribute__((ext_vector_type(4))) float f32x4;

__device__ __forceinline__ u16 f2bf(float f) {          // RNE fp32->bf16
  unsigned int u = __float_as_uint(f);
  u += 0x7fffu + ((u >> 16) & 1u);
  return (u16)(u >> 16);
}

// ---- prep + bucket fused: bucket's atomic latency hides under prep streaming
__global__ __launch_bounds__(256) void prep_bucket_kernel(
    const float* __restrict__ x, const int* __restrict__ ei,
    const float* __restrict__ W1, const float* __restrict__ W2,
    const float* __restrict__ Wres,
    u16* __restrict__ xh, u16* __restrict__ wt,
    int* __restrict__ tail, unsigned* __restrict__ buf) {
  __shared__ int lhist[NB], lbase[NB];
  int b = blockIdx.x;
  int t = threadIdx.x;
  if (b < 12500) {                     // x convert: 3.2M float4s
    int q = b * 256 + t;
    float4 v = ((const float4*)x)[q];
    uint2 pk;
    pk.x = (unsigned)f2bf(v.x) | ((unsigned)f2bf(v.y) << 16);
    pk.y = (unsigned)f2bf(v.z) | ((unsigned)f2bf(v.w) << 16);
    ((uint2*)xh)[q] = pk;
  } else if (b < PB) {                 // W transpose: order [Wres, W1, W2]
    const float* W = (b == 12500) ? Wres : (b == 12501) ? W1 : W2;
    u16* dst = wt + (size_t)(b - 12500) * 16384;
    for (int i = t; i < 16384; i += 256) {
      int n = i >> 7, k = i & 127;
      dst[i] = f2bf(W[k * 128 + n]);   // dst[n*128+k]
    }
  } else {                             // bucket edges by dst>>9 (tail pre-zeroed)
    size_t e0 = (size_t)(b - PB) * 4096;
    int s[16], d[16];
    for (int j = t; j < NB; j += 256) lhist[j] = 0;
    __syncthreads();
#pragma unroll
    for (int k = 0; k < 16; ++k) {
      size_t e = e0 + t + (size_t)k * 256;
      if (e < NE) {
        d[k] = ei[NE + e];             // dst
        s[k] = ei[e];                  // src
        atomicAdd(&lhist[d[k] >> 9], 1);  // LDS, no-return -> ds_add
      } else {
        d[k] = -1;
      }
    }
    __syncthreads();
    for (int j = t; j < NB; j += 256) {  // reserve contiguous run per bucket
      int c = lhist[j];
      lbase[j] = c ? atomicAdd(&tail[j], c) : 0;
      lhist[j] = 0;
    }
    __syncthreads();
#pragma unroll
    for (int k = 0; k < 16; ++k) {
      if (d[k] >= 0) {
        int bk = d[k] >> 9;
        int r = lbase[bk] + atomicAdd(&lhist[bk], 1);
        if (r < CAP)
          buf[(size_t)bk * CAP + r] = (unsigned)s[k] | ((unsigned)(d[k] & 511) << 17);
      }
    }
  }
}

// ---------------- per-bucket CSR build, all atomics in LDS ----------------
__global__ __launch_bounds__(512) void build_csr(const unsigned* __restrict__ buf,
                                                 const int* __restrict__ tail,
                                                 int* __restrict__ cnt,
                                                 int* __restrict__ start,
                                                 int* __restrict__ csr) {
  __shared__ int lhist[512], lpre[512], lsum[64];
  int b = blockIdx.x, t = threadIdx.x;
  int nE = tail[b];
  if (nE > CAP) nE = CAP;
  size_t bBase = (size_t)b * CAP;
  lhist[t] = 0;
  __syncthreads();
  for (int i = t; i < nE; i += 512)
    atomicAdd(&lhist[buf[bBase + i] >> 17], 1);
  __syncthreads();
  if (t < 64) {
    int s = 0;
#pragma unroll
    for (int k = 0; k < 8; ++k) { int v = lhist[t * 8 + k]; lpre[t * 8 + k] = s; s += v; }
    lsum[t] = s;
  }
  __syncthreads();
  if (t == 0) {
    int s = 0;
    for (int k = 0; k < 64; ++k) { int v = lsum[k]; lsum[k] = s; s += v; }
  }
  __syncthreads();
  if (t < 64) {
    int o = lsum[t];
#pragma unroll
    for (int k = 0; k < 8; ++k) lpre[t * 8 + k] += o;
  }
  __syncthreads();
  int node = (b << 9) + t;
  if (node < NN) {
    cnt[node] = lhist[t];
    start[node] = (int)bBase + lpre[t];
  }
  lhist[t] = 0;
  __syncthreads();
  for (int i = t; i < nE; i += 512) {
    unsigned e = buf[bBase + i];
    int dl = e >> 17;
    int r = atomicAdd(&lhist[dl], 1);                 // LDS rank
    csr[bBase + lpre[dl] + r] = (int)(e & 0x1FFFFu);  // L2-resident 36KB window
  }
}

// ---- gather: h0h[n] = bf16(x[n] + sum xh[csr[...]]) -> first 256B of out row
// 16 lanes x uint4(16B) per row: half the loads, 2x outstanding bytes vs 32x8B.
#define BFACC8(aL, aH, v)                                  \
  { aL.x += __uint_as_float((v).x << 16);                  \
    aL.y += __uint_as_float((v).x & 0xffff0000u);          \
    aL.z += __uint_as_float((v).y << 16);                  \
    aL.w += __uint_as_float((v).y & 0xffff0000u);          \
    aH.x += __uint_as_float((v).z << 16);                  \
    aH.y += __uint_as_float((v).z & 0xffff0000u);          \
    aH.z += __uint_as_float((v).w << 16);                  \
    aH.w += __uint_as_float((v).w & 0xffff0000u); }

__global__ __launch_bounds__(256, 6) void gather_kernel(const float* __restrict__ x,
                                                        const u16* __restrict__ xh,
                                                        const int* __restrict__ cnt,
                                                        const int* __restrict__ start,
                                                        const int* __restrict__ csr,
                                                        u16* __restrict__ h0h) {
  int g = blockIdx.x * 16 + (threadIdx.x >> 4);
  if (g >= NN) return;
  int lane = threadIdx.x & 15;
  int fo = lane * 8;                   // u16 units: 16 B per lane
  int n = cnt[g];
  const int* sp = csr + start[g];

  float4 aL0 = make_float4(0.f, 0.f, 0.f, 0.f);
  float4 aH0 = aL0, aL1 = aL0, aH1 = aL0;

  int nfull = n & ~3;
  if (nfull > 0) {
    int s0 = sp[0], s1 = sp[1], s2 = sp[2], s3 = sp[3];
    uint4 v0 = *(const uint4*)&xh[(size_t)s0 * D + fo];
    uint4 v1 = *(const uint4*)&xh[(size_t)s1 * D + fo];
    uint4 v2 = *(const uint4*)&xh[(size_t)s2 * D + fo];
    uint4 v3 = *(const uint4*)&xh[(size_t)s3 * D + fo];
#pragma unroll 2
    for (int j = 4; j < nfull; j += 4) {
      int t0 = sp[j], t1 = sp[j + 1], t2 = sp[j + 2], t3 = sp[j + 3];
      uint4 w0 = *(const uint4*)&xh[(size_t)t0 * D + fo];
      uint4 w1 = *(const uint4*)&xh[(size_t)t1 * D + fo];
      uint4 w2 = *(const uint4*)&xh[(size_t)t2 * D + fo];
      uint4 w3 = *(const uint4*)&xh[(size_t)t3 * D + fo];
      BFACC8(aL0, aH0, v0); BFACC8(aL1, aH1, v1);
      BFACC8(aL0, aH0, v2); BFACC8(aL1, aH1, v3);
      v0 = w0; v1 = w1; v2 = w2; v3 = w3;
    }
    BFACC8(aL0, aH0, v0); BFACC8(aL1, aH1, v1);
    BFACC8(aL0, aH0, v2); BFACC8(aL1, aH1, v3);
  }
  for (int j = nfull; j < n; ++j) {
    uint4 v0 = *(const uint4*)&xh[(size_t)sp[j] * D + fo];
    BFACC8(aL0, aH0, v0);
  }

  const float* xp = &x[(size_t)g * D + fo];   // self term exact
  float4 x0 = *(const float4*)xp;
  float4 x1 = *(const float4*)(xp + 4);
  float h0 = x0.x + aL0.x + aL1.x;
  float h1 = x0.y + aL0.y + aL1.y;
  float h2 = x0.z + aL0.z + aL1.z;
  float h3 = x0.w + aL0.w + aL1.w;
  float h4 = x1.x + aH0.x + aH1.x;
  float h5 = x1.y + aH0.y + aH1.y;
  float h6 = x1.z + aH0.z + aH1.z;
  float h7 = x1.w + aH0.w + aH1.w;
  uint4 pk;
  pk.x = (unsigned)f2bf(h0) | ((unsigned)f2bf(h1) << 16);
  pk.y = (unsigned)f2bf(h2) | ((unsigned)f2bf(h3) << 16);
  pk.z = (unsigned)f2bf(h4) | ((unsigned)f2bf(h5) << 16);
  pk.w = (unsigned)f2bf(h6) | ((unsigned)f2bf(h7) << 16);
  *(uint4*)&h0h[(size_t)g * 256 + fo] = pk;   // row stride 256 u16 = 512 B
}

// ---------------- fused MFMA: 3 GEMMs + ReLU + LN + residual ----------------
// Hs staged from bf16 h0h; Wres GEMM A-frags straight from global xh (L3-hot).
// 3 barriers. C/D layout (verified): col=lane&15, row=(lane>>4)*4+reg.
// launch_bounds(256,4): VGPR cap 128 -- (256,6) capped at ~85 and SPILLED the
// 64-VGPR accumulator state to scratch (R3: VGPR=40, +75MB WRITE, +130MB FETCH).
__global__ __launch_bounds__(256, 4) void fused_kernel(
    const u16* __restrict__ xh, const u16* __restrict__ h0h,
    const u16* __restrict__ wt,
    const float* __restrict__ b1, const float* __restrict__ b2,
    const float* __restrict__ gamma, const float* __restrict__ beta,
    const float* __restrict__ bres, float* __restrict__ out) {
  __shared__ u16 Hs[RT * PADB];   // 17408 B

  const int t = threadIdx.x;
  const int w = t >> 6;
  const int lane = t & 63;
  const int quad = lane >> 4;
  const int l16 = lane & 15;
  const int row0 = blockIdx.x * RT;

  // stage Hs <- h0h (bf16 rows, stride 256 u16)
#pragma unroll
  for (int i = 0; i < 8; ++i) {
    int v = t + i * 256;
    int r = v >> 5;
    int c4 = (v & 31) << 2;
    int row = row0 + r;
    uint2 val = make_uint2(0u, 0u);
    if (row < NN) val = *(const uint2*)&h0h[(size_t)row * 256 + c4];
    *(uint2*)&Hs[r * PADB + c4] = val;
  }

  f32x4 acc[8], accR[8];
  f32x4 zz = {0.f, 0.f, 0.f, 0.f};
#pragma unroll
  for (int i = 0; i < 8; ++i) { acc[i] = zz; accR[i] = zz; }

  auto gemmL = [&](const u16* __restrict__ W, f32x4 (&dd)[8]) {   // A from LDS
    bf16x8 af[4];
#pragma unroll
    for (int s = 0; s < 4; ++s)
      af[s] = *(const bf16x8*)&Hs[(w * 16 + l16) * PADB + s * 32 + quad * 8];
#pragma unroll
    for (int nt = 0; nt < 8; ++nt) {
      const u16* wp = W + (size_t)(nt * 16 + l16) * D + quad * 8;
#pragma unroll
      for (int s = 0; s < 4; ++s) {
        bf16x8 bf = *(const bf16x8*)&wp[s * 32];
        dd[nt] = __builtin_amdgcn_mfma_f32_16x16x32_bf16(af[s], bf, dd[nt], 0, 0, 0);
      }
    }
  };

  {  // Wres GEMM: A straight from global xh (overlaps the stage, pre-barrier)
    bf16x8 af[4];
#pragma unroll
    for (int s = 0; s < 4; ++s)
      af[s] = *(const bf16x8*)&xh[(size_t)(row0 + w * 16 + l16) * D + s * 32 + quad * 8];
#pragma unroll
    for (int nt = 0; nt < 8; ++nt) {
      const u16* wp = wt + (size_t)(nt * 16 + l16) * D + quad * 8;
#pragma unroll
      for (int s = 0; s < 4; ++s) {
        bf16x8 bf = *(const bf16x8*)&wp[s * 32];
        accR[nt] = __builtin_amdgcn_mfma_f32_16x16x32_bf16(af[s], bf, accR[nt], 0, 0, 0);
      }
    }
  }

  __syncthreads();                // Hs ready
  gemmL(wt + 16384, acc);         // W1 on Hs
  __syncthreads();                // af loads done before Hs overwrite

  // ---- h1 = relu(acc + b1) -> Hs (C-layout scatter, bf16) ----
#pragma unroll
  for (int nt = 0; nt < 8; ++nt) {
    int col = nt * 16 + l16;
    float bb = b1[col];
#pragma unroll
    for (int r = 0; r < 4; ++r) {
      float hv = acc[nt][r] + bb;
      hv = hv > 0.f ? hv : 0.f;
      Hs[(w * 16 + quad * 4 + r) * PADB + col] = f2bf(hv);
      acc[nt][r] = 0.f;
    }
  }
  __syncthreads();
  gemmL(wt + 32768, acc);         // W2

  // ---- epilogue: +b2, LayerNorm (shuffle over 16-lane quad), + residual ----
  float b2v[8], gv[8], bev[8], brv[8];
#pragma unroll
  for (int nt = 0; nt < 8; ++nt) {
    int col = nt * 16 + l16;
    b2v[nt] = b2[col];
    gv[nt] = gamma[col];
    bev[nt] = beta[col];
    brv[nt] = bres[col];
  }
#pragma unroll
  for (int r = 0; r < 4; ++r) {
    float s = 0.f, s2 = 0.f;
#pragma unroll
    for (int nt = 0; nt < 8; ++nt) {
      float h = acc[nt][r] + b2v[nt];
      s += h;
      s2 += h * h;
    }
    for (int m = 1; m <= 8; m <<= 1) {   // reduce across the quad's 16 lanes
      s += __shfl_xor(s, m);
      s2 += __shfl_xor(s2, m);
    }
    float mu = s * 0.0078125f;
    float var = s2 * 0.0078125f - mu * mu;
    float rs = rsqrtf(var + 1e-5f);
    int row = row0 + w * 16 + quad * 4 + r;
    if (row < NN) {
#pragma unroll
      for (int nt = 0; nt < 8; ++nt) {
        float h = acc[nt][r] + b2v[nt];
        out[(size_t)row * D + nt * 16 + l16] =
            (h - mu) * rs * gv[nt] + bev[nt] + accR[nt][r] + brv[nt];
      }
    }
  }
}

extern "C" void kernel_launch(void* const* d_in, const int* in_sizes, int n_in,
                              void* d_out, int out_size, void* d_ws, size_t ws_size,
                              hipStream_t stream) {
  const float* x     = (const float*)d_in[0];
  const int*   ei    = (const int*)d_in[1];
  const float* W1    = (const float*)d_in[2];
  const float* b1    = (const float*)d_in[3];
  const float* W2    = (const float*)d_in[4];
  const float* b2    = (const float*)d_in[5];
  const float* gamma = (const float*)d_in[6];
  const float* beta  = (const float*)d_in[7];
  const float* Wres  = (const float*)d_in[8];
  const float* bres  = (const float*)d_in[9];
  float* out = (float*)d_out;

  // ws: tail 1KB | buf 7.2MB | cnt 0.4 | start 0.4 | csr 7.2 | xh 25.6 | wt 96KB
  int*      tail  = (int*)d_ws;                              // 256 (NB=196 used)
  unsigned* buf   = (unsigned*)(tail + 256);                 // NB*CAP
  int*      cnt   = (int*)(buf + (size_t)NB * CAP);          // NN
  int*      start = cnt + NN;                                // NN
  int*      csr   = start + NN;                              // NB*CAP
  u16*      xh    = (u16*)(csr + (size_t)NB * CAP);          // NN*D bf16
  u16*      wt    = xh + (size_t)NN * D;                     // 3*128*128 bf16

  // h0 (bf16) lives in the first 256 B of each 512 B out-row slot: block i of
  // fused reads exactly the rows it later overwrites -> race-free.
  u16* h0h = (u16*)out;

  hipMemsetAsync(tail, 0, 256 * sizeof(int), stream);
  prep_bucket_kernel<<<PB + BUCKB, 256, 0, stream>>>(x, ei, W1, W2, Wres,
                                                     xh, wt, tail, buf);
  build_csr<<<NB, 512, 0, stream>>>(buf, tail, cnt, start, csr);
  gather_kernel<<<(NN + 15) / 16, 256, 0, stream>>>(x, xh, cnt, start, csr, h0h);
  fused_kernel<<<(NN + RT - 1) / RT, 256, 0, stream>>>(
      xh, h0h, wt, b1, b2, gamma, beta, bres, out);
}

// Round 5
// 255.975 us; speedup vs baseline: 1.4835x; 1.2412x over previous
//
#include <hip/hip_runtime.h>

#define NN 100000
#define NE 1600000
#define D 128
#define RT 64
#define NB 196      // dst buckets of 512 nodes: ceil(100000/512)
#define CAP 9216    // per-bucket edge cap: mean 8192, sd ~90 -> +11 sigma
#define PADB 136    // bf16 elems per LDS row: b128 frag reads 2-way (free)
#define PB 12503    // blocks 0..PB-1: x convert + W transpose; then bucket blocks
#define BUCKB 391   // bucket blocks x 4096 edges = 1601536 >= NE

typedef unsigned short u16;
typedef __attribute__((ext_vector_type(8))) short bf16x8;
typedef __attribute__((ext_vector_type(4))) float f32x4;

__device__ __forceinline__ u16 f2bf(float f) {          // RNE fp32->bf16
  unsigned int u = __float_as_uint(f);
  u += 0x7fffu + ((u >> 16) & 1u);
  return (u16)(u >> 16);
}

// ---- prep + bucket fused: bucket's atomic latency hides under prep streaming
__global__ __launch_bounds__(256) void prep_bucket_kernel(
    const float* __restrict__ x, const int* __restrict__ ei,
    const float* __restrict__ W1, const float* __restrict__ W2,
    const float* __restrict__ Wres,
    u16* __restrict__ xh, u16* __restrict__ wt,
    int* __restrict__ tail, unsigned* __restrict__ buf) {
  __shared__ int lhist[NB], lbase[NB];
  int b = blockIdx.x;
  int t = threadIdx.x;
  if (b < 12500) {                     // x convert: 3.2M float4s
    int q = b * 256 + t;
    float4 v = ((const float4*)x)[q];
    uint2 pk;
    pk.x = (unsigned)f2bf(v.x) | ((unsigned)f2bf(v.y) << 16);
    pk.y = (unsigned)f2bf(v.z) | ((unsigned)f2bf(v.w) << 16);
    ((uint2*)xh)[q] = pk;
  } else if (b < PB) {                 // W transpose: order [Wres, W1, W2]
    const float* W = (b == 12500) ? Wres : (b == 12501) ? W1 : W2;
    u16* dst = wt + (size_t)(b - 12500) * 16384;
    for (int i = t; i < 16384; i += 256) {
      int n = i >> 7, k = i & 127;
      dst[i] = f2bf(W[k * 128 + n]);   // dst[n*128+k]
    }
  } else {                             // bucket edges by dst>>9 (tail pre-zeroed)
    size_t e0 = (size_t)(b - PB) * 4096;
    int s[16], d[16];
    for (int j = t; j < NB; j += 256) lhist[j] = 0;
    __syncthreads();
#pragma unroll
    for (int k = 0; k < 16; ++k) {
      size_t e = e0 + t + (size_t)k * 256;
      if (e < NE) {
        d[k] = ei[NE + e];             // dst
        s[k] = ei[e];                  // src
        atomicAdd(&lhist[d[k] >> 9], 1);  // LDS, no-return -> ds_add
      } else {
        d[k] = -1;
      }
    }
    __syncthreads();
    for (int j = t; j < NB; j += 256) {  // reserve contiguous run per bucket
      int c = lhist[j];
      lbase[j] = c ? atomicAdd(&tail[j], c) : 0;
      lhist[j] = 0;
    }
    __syncthreads();
#pragma unroll
    for (int k = 0; k < 16; ++k) {
      if (d[k] >= 0) {
        int bk = d[k] >> 9;
        int r = lbase[bk] + atomicAdd(&lhist[bk], 1);
        if (r < CAP)
          buf[(size_t)bk * CAP + r] = (unsigned)s[k] | ((unsigned)(d[k] & 511) << 17);
      }
    }
  }
}

// ---------------- per-bucket CSR build, all atomics in LDS ----------------
__global__ __launch_bounds__(512) void build_csr(const unsigned* __restrict__ buf,
                                                 const int* __restrict__ tail,
                                                 int* __restrict__ cnt,
                                                 int* __restrict__ start,
                                                 int* __restrict__ csr) {
  __shared__ int lhist[512], lpre[512], lsum[64];
  int b = blockIdx.x, t = threadIdx.x;
  int nE = tail[b];
  if (nE > CAP) nE = CAP;
  size_t bBase = (size_t)b * CAP;
  lhist[t] = 0;
  __syncthreads();
  for (int i = t; i < nE; i += 512)
    atomicAdd(&lhist[buf[bBase + i] >> 17], 1);
  __syncthreads();
  if (t < 64) {
    int s = 0;
#pragma unroll
    for (int k = 0; k < 8; ++k) { int v = lhist[t * 8 + k]; lpre[t * 8 + k] = s; s += v; }
    lsum[t] = s;
  }
  __syncthreads();
  if (t == 0) {
    int s = 0;
    for (int k = 0; k < 64; ++k) { int v = lsum[k]; lsum[k] = s; s += v; }
  }
  __syncthreads();
  if (t < 64) {
    int o = lsum[t];
#pragma unroll
    for (int k = 0; k < 8; ++k) lpre[t * 8 + k] += o;
  }
  __syncthreads();
  int node = (b << 9) + t;
  if (node < NN) {
    cnt[node] = lhist[t];
    start[node] = (int)bBase + lpre[t];
  }
  lhist[t] = 0;
  __syncthreads();
  for (int i = t; i < nE; i += 512) {
    unsigned e = buf[bBase + i];
    int dl = e >> 17;
    int r = atomicAdd(&lhist[dl], 1);                 // LDS rank
    csr[bBase + lpre[dl] + r] = (int)(e & 0x1FFFFu);  // L2-resident 36KB window
  }
}

// ---- gather: h0h[n] = bf16(x[n] + sum xh[csr[...]]) -> first 256B of out row
#define BFACC8(aL, aH, v)                                  \
  { aL.x += __uint_as_float((v).x << 16);                  \
    aL.y += __uint_as_float((v).x & 0xffff0000u);          \
    aL.z += __uint_as_float((v).y << 16);                  \
    aL.w += __uint_as_float((v).y & 0xffff0000u);          \
    aH.x += __uint_as_float((v).z << 16);                  \
    aH.y += __uint_as_float((v).z & 0xffff0000u);          \
    aH.z += __uint_as_float((v).w << 16);                  \
    aH.w += __uint_as_float((v).w & 0xffff0000u); }

__global__ __launch_bounds__(256, 6) void gather_kernel(const float* __restrict__ x,
                                                        const u16* __restrict__ xh,
                                                        const int* __restrict__ cnt,
                                                        const int* __restrict__ start,
                                                        const int* __restrict__ csr,
                                                        u16* __restrict__ h0h) {
  int g = blockIdx.x * 16 + (threadIdx.x >> 4);
  if (g >= NN) return;
  int lane = threadIdx.x & 15;
  int fo = lane * 8;                   // u16 units: 16 B per lane
  int n = cnt[g];
  const int* sp = csr + start[g];

  float4 aL0 = make_float4(0.f, 0.f, 0.f, 0.f);
  float4 aH0 = aL0, aL1 = aL0, aH1 = aL0;

  int nfull = n & ~3;
  if (nfull > 0) {
    int s0 = sp[0], s1 = sp[1], s2 = sp[2], s3 = sp[3];
    uint4 v0 = *(const uint4*)&xh[(size_t)s0 * D + fo];
    uint4 v1 = *(const uint4*)&xh[(size_t)s1 * D + fo];
    uint4 v2 = *(const uint4*)&xh[(size_t)s2 * D + fo];
    uint4 v3 = *(const uint4*)&xh[(size_t)s3 * D + fo];
#pragma unroll 2
    for (int j = 4; j < nfull; j += 4) {
      int t0 = sp[j], t1 = sp[j + 1], t2 = sp[j + 2], t3 = sp[j + 3];
      uint4 w0 = *(const uint4*)&xh[(size_t)t0 * D + fo];
      uint4 w1 = *(const uint4*)&xh[(size_t)t1 * D + fo];
      uint4 w2 = *(const uint4*)&xh[(size_t)t2 * D + fo];
      uint4 w3 = *(const uint4*)&xh[(size_t)t3 * D + fo];
      BFACC8(aL0, aH0, v0); BFACC8(aL1, aH1, v1);
      BFACC8(aL0, aH0, v2); BFACC8(aL1, aH1, v3);
      v0 = w0; v1 = w1; v2 = w2; v3 = w3;
    }
    BFACC8(aL0, aH0, v0); BFACC8(aL1, aH1, v1);
    BFACC8(aL0, aH0, v2); BFACC8(aL1, aH1, v3);
  }
  for (int j = nfull; j < n; ++j) {
    uint4 v0 = *(const uint4*)&xh[(size_t)sp[j] * D + fo];
    BFACC8(aL0, aH0, v0);
  }

  const float* xp = &x[(size_t)g * D + fo];   // self term exact
  float4 x0 = *(const float4*)xp;
  float4 x1 = *(const float4*)(xp + 4);
  float h0 = x0.x + aL0.x + aL1.x;
  float h1 = x0.y + aL0.y + aL1.y;
  float h2 = x0.z + aL0.z + aL1.z;
  float h3 = x0.w + aL0.w + aL1.w;
  float h4 = x1.x + aH0.x + aH1.x;
  float h5 = x1.y + aH0.y + aH1.y;
  float h6 = x1.z + aH0.z + aH1.z;
  float h7 = x1.w + aH0.w + aH1.w;
  uint4 pk;
  pk.x = (unsigned)f2bf(h0) | ((unsigned)f2bf(h1) << 16);
  pk.y = (unsigned)f2bf(h2) | ((unsigned)f2bf(h3) << 16);
  pk.z = (unsigned)f2bf(h4) | ((unsigned)f2bf(h5) << 16);
  pk.w = (unsigned)f2bf(h6) | ((unsigned)f2bf(h7) << 16);
  *(uint4*)&h0h[(size_t)g * 256 + fo] = pk;   // row stride 256 u16 = 512 B
}

// ---------------- fused MFMA: 3 GEMMs + ReLU + LN + residual ----------------
// KEY CHANGE (R5): B operands now come from LDS (Ws, staged cooperatively and
// coalesced once per GEMM phase) instead of 32 scattered global loads per wave
// per GEMM -- R1/R4's 96us was per-wave L2-latency serialization on B-frags
// (MfmaUtil 3.8%, VALU 7%, HBM 10%: pure stall). A-frags for Wres/W1 read
// straight from global xh/h0h (4 independent loads/wave, row-clamped at NN).
// Hs only holds the ReLU intermediate now. LDS 52.2KB -> 3 blocks/CU.
// C/D layout (verified): col=lane&15, row=(lane>>4)*4+reg.
__global__ __launch_bounds__(256, 3) void fused_kernel(
    const u16* __restrict__ xh, const u16* __restrict__ h0h,
    const u16* __restrict__ wt,
    const float* __restrict__ b1, const float* __restrict__ b2,
    const float* __restrict__ gamma, const float* __restrict__ beta,
    const float* __restrict__ bres, float* __restrict__ out) {
  __shared__ u16 Ws[128 * PADB];  // 34816 B: current weight matrix, padded
  __shared__ u16 Hs[RT * PADB];   // 17408 B: ReLU intermediate

  const int t = threadIdx.x;
  const int w = t >> 6;
  const int lane = t & 63;
  const int quad = lane >> 4;
  const int l16 = lane & 15;
  const int row0 = blockIdx.x * RT;

  auto stageW = [&](const u16* __restrict__ src) {   // 32KB coalesced -> Ws
#pragma unroll
    for (int i = 0; i < 16; ++i) {
      int v = t + i * 256;
      int r = v >> 5;
      int c4 = (v & 31) << 2;
      *(uint2*)&Ws[r * PADB + c4] = *(const uint2*)&src[r * D + c4];
    }
  };

  f32x4 acc[8], accR[8];
  f32x4 zz = {0.f, 0.f, 0.f, 0.f};
#pragma unroll
  for (int i = 0; i < 8; ++i) { acc[i] = zz; accR[i] = zz; }

  // A from global (stride in u16 elems), B from Ws LDS
  auto gemmGA = [&](const u16* __restrict__ Ag, int astride, f32x4 (&dd)[8]) {
    bf16x8 af[4];
    int ar = row0 + w * 16 + l16;
    if (ar > NN - 1) ar = NN - 1;      // clamp: garbage rows discarded at write
#pragma unroll
    for (int s = 0; s < 4; ++s)
      af[s] = *(const bf16x8*)&Ag[(size_t)ar * astride + s * 32 + quad * 8];
#pragma unroll
    for (int nt = 0; nt < 8; ++nt) {
      const u16* wp = &Ws[(nt * 16 + l16) * PADB + quad * 8];
#pragma unroll
      for (int s = 0; s < 4; ++s) {
        bf16x8 bf = *(const bf16x8*)&wp[s * 32];
        dd[nt] = __builtin_amdgcn_mfma_f32_16x16x32_bf16(af[s], bf, dd[nt], 0, 0, 0);
      }
    }
  };
  // A from Hs LDS, B from Ws LDS
  auto gemmLA = [&](f32x4 (&dd)[8]) {
    bf16x8 af[4];
#pragma unroll
    for (int s = 0; s < 4; ++s)
      af[s] = *(const bf16x8*)&Hs[(w * 16 + l16) * PADB + s * 32 + quad * 8];
#pragma unroll
    for (int nt = 0; nt < 8; ++nt) {
      const u16* wp = &Ws[(nt * 16 + l16) * PADB + quad * 8];
#pragma unroll
      for (int s = 0; s < 4; ++s) {
        bf16x8 bf = *(const bf16x8*)&wp[s * 32];
        dd[nt] = __builtin_amdgcn_mfma_f32_16x16x32_bf16(af[s], bf, dd[nt], 0, 0, 0);
      }
    }
  };

  stageW(wt);                     // Wres
  __syncthreads();                // b1: Ws ready
  gemmGA(xh, D, accR);            // Wres GEMM, A rows from global xh
  __syncthreads();                // b2: Ws reads done
  stageW(wt + 16384);             // W1
  __syncthreads();                // b3: Ws ready
  gemmGA(h0h, 256, acc);          // W1 GEMM, A rows from global h0h (bf16)
  __syncthreads();                // b4: Ws reads done

  // ---- h1 = relu(acc + b1) -> Hs (C-layout scatter) + stage W2 (overlap) ----
#pragma unroll
  for (int nt = 0; nt < 8; ++nt) {
    int col = nt * 16 + l16;
    float bb = b1[col];
#pragma unroll
    for (int r = 0; r < 4; ++r) {
      float hv = acc[nt][r] + bb;
      hv = hv > 0.f ? hv : 0.f;
      Hs[(w * 16 + quad * 4 + r) * PADB + col] = f2bf(hv);
      acc[nt][r] = 0.f;
    }
  }
  stageW(wt + 32768);             // W2 (writes Ws; Hs writes above independent)
  __syncthreads();                // b5: Hs + Ws ready
  gemmLA(acc);                    // W2 GEMM, A from Hs

  // ---- epilogue: +b2, LayerNorm (shuffle over 16-lane quad), + residual ----
  float b2v[8], gv[8], bev[8], brv[8];
#pragma unroll
  for (int nt = 0; nt < 8; ++nt) {
    int col = nt * 16 + l16;
    b2v[nt] = b2[col];
    gv[nt] = gamma[col];
    bev[nt] = beta[col];
    brv[nt] = bres[col];
  }
#pragma unroll
  for (int r = 0; r < 4; ++r) {
    float s = 0.f, s2 = 0.f;
#pragma unroll
    for (int nt = 0; nt < 8; ++nt) {
      float h = acc[nt][r] + b2v[nt];
      s += h;
      s2 += h * h;
    }
    for (int m = 1; m <= 8; m <<= 1) {   // reduce across the quad's 16 lanes
      s += __shfl_xor(s, m);
      s2 += __shfl_xor(s2, m);
    }
    float mu = s * 0.0078125f;
    float var = s2 * 0.0078125f - mu * mu;
    float rs = rsqrtf(var + 1e-5f);
    int row = row0 + w * 16 + quad * 4 + r;
    if (row < NN) {
#pragma unroll
      for (int nt = 0; nt < 8; ++nt) {
        float h = acc[nt][r] + b2v[nt];
        out[(size_t)row * D + nt * 16 + l16] =
            (h - mu) * rs * gv[nt] + bev[nt] + accR[nt][r] + brv[nt];
      }
    }
  }
}

extern "C" void kernel_launch(void* const* d_in, const int* in_sizes, int n_in,
                              void* d_out, int out_size, void* d_ws, size_t ws_size,
                              hipStream_t stream) {
  const float* x     = (const float*)d_in[0];
  const int*   ei    = (const int*)d_in[1];
  const float* W1    = (const float*)d_in[2];
  const float* b1    = (const float*)d_in[3];
  const float* W2    = (const float*)d_in[4];
  const float* b2    = (const float*)d_in[5];
  const float* gamma = (const float*)d_in[6];
  const float* beta  = (const float*)d_in[7];
  const float* Wres  = (const float*)d_in[8];
  const float* bres  = (const float*)d_in[9];
  float* out = (float*)d_out;

  // ws: tail 1KB | buf 7.2MB | cnt 0.4 | start 0.4 | csr 7.2 | xh 25.6 | wt 96KB
  int*      tail  = (int*)d_ws;                              // 256 (NB=196 used)
  unsigned* buf   = (unsigned*)(tail + 256);                 // NB*CAP
  int*      cnt   = (int*)(buf + (size_t)NB * CAP);          // NN
  int*      start = cnt + NN;                                // NN
  int*      csr   = start + NN;                              // NB*CAP
  u16*      xh    = (u16*)(csr + (size_t)NB * CAP);          // NN*D bf16
  u16*      wt    = xh + (size_t)NN * D;                     // 3*128*128 bf16

  // h0 (bf16) lives in the first 256 B of each 512 B out-row slot: block i of
  // fused reads exactly the rows it later overwrites -> race-free.
  u16* h0h = (u16*)out;

  hipMemsetAsync(tail, 0, 256 * sizeof(int), stream);
  prep_bucket_kernel<<<PB + BUCKB, 256, 0, stream>>>(x, ei, W1, W2, Wres,
                                                     xh, wt, tail, buf);
  build_csr<<<NB, 512, 0, stream>>>(buf, tail, cnt, start, csr);
  gather_kernel<<<(NN + 15) / 16, 256, 0, stream>>>(x, xh, cnt, start, csr, h0h);
  fused_kernel<<<(NN + RT - 1) / RT, 256, 0, stream>>>(
      xh, h0h, wt, b1, b2, gamma, beta, bres, out);
}